// Round 1
// baseline (30811.041 us; speedup 1.0000x reference)
//
#include <hip/hip_runtime.h>
#include <cstdint>
#include <cstddef>

// ---------------- constants ----------------
static constexpr int NIMG = 2;
static constexpr int CCH  = 256;                  // channels
static constexpr int LTOT = 261888;               // sum H*W*3 over levels
static constexpr int MCAT = 4768;                 // 1000*4 + 768
static constexpr int MW   = 75;                   // ceil(4768/64)
static constexpr double SCALE_CLAMP_D = 4.135166556742356; // ln(1000/16)

// BITWISE CONSTRAINT (learned R4): the harness np-reference is fp32 and our
// conv matched it bitwise (absmax exactly 0.0). Sorted-score spacing
// (~7.7e-4) makes any logit error >~1e-7 flip ranks -> huge absmax. So the
// conv MUST remain sequential fp32 FMA in (cin ascending, kh, kw) order.
// No MFMA, no K-splitting, no reassociation. Optimize resources only.
//
// R5 change: VALUBusy 96% is inflated ~2x (gfx94x SIMD-16 derived formula on
// SIMD-32 gfx950); true VALU ~48%, FMA ~40% of cycles -> kernel was
// barrier/phase-lock stalled, not VALU-bound. Restructure:
//   - x tile double-buffered in LDS (one barrier per ck, not two)
//   - T14: next-ck global loads issued BEFORE compute, ds_write after
//   - weights read directly from L2-resident wT (wsm LDS staging removed)
//   - staging address math (div 66, bounds) hoisted out of the ck loop
// FMA order unchanged -> bitwise-identical output.

// ---------------- key helpers (descending-order monotone uint key) --------
__device__ __forceinline__ unsigned keyd(float f) {
  unsigned u = __float_as_uint(f);
  return (u >> 31) ? ~u : (u | 0x80000000u);
}
__device__ __forceinline__ float invkey(unsigned d) {
  unsigned u = (d & 0x80000000u) ? (d & 0x7FFFFFFFu) : ~d;
  return __uint_as_float(u);
}

// ---------------- K0: transpose conv weights [O][I][3][3] -> [I*9][O] -----
__global__ void k_wT(const float* __restrict__ w, float* __restrict__ wT) {
  int i = blockIdx.x * 256 + threadIdx.x;
  if (i >= 2304 * 256) return;
  int co = i & 255;
  int ct = i >> 8;                 // ci*9 + tap
  wT[ct * 256 + co] = w[co * 2304 + ct];
}

// ---------------- conv3x3 + bias + relu (fp32, bitwise-pinned) ------------
// Block tile: 64 couts x (4 rows x 64 cols). 256 threads, each 4co x 16px.
__device__ __forceinline__ void conv_body(
    const float* __restrict__ x, const float* __restrict__ wT,
    const float* __restrict__ bias, float* __restrict__ t,
    int H, int W, int n, int cog, int h0, int w0) {
  // x tile, double-buffered: 6 halo rows x 66 halo cols (stride 76 = 16B
  // aligned rows + bank spread). 2*8*6*76*4 = 29184 B LDS.
  __shared__ __align__(16) float xs[2][8][6][76];

  const int cout0 = cog * 64;
  const int tx = threadIdx.x;
  const int cog4 = tx >> 4;        // 0..15 -> couts cout0+cog4*4 ..+3
  const int pxg  = tx & 15;
  const int r2   = pxg >> 4 == 0 ? (pxg >> 2) : 0; // = pxg>>2 (0..3)
  const int col0 = (pxg & 3) * 16; // col group (16 px per thread)
  const int HWi  = H * W;

  // ---- ck-invariant staging geometry: elems e in {tx, tx+256} of 396=6*66
  const int e0 = tx;
  const int e1 = tx + 256;
  const int ra = e0 / 66, ca = e0 - ra * 66;
  const int rb = e1 / 66, cb = e1 - rb * 66;      // only used when tx < 140
  const int gha = h0 - 1 + ra, gwa = w0 - 1 + ca;
  const int ghb = h0 - 1 + rb, gwb = w0 - 1 + cb;
  const bool va = (unsigned)gha < (unsigned)H && (unsigned)gwa < (unsigned)W;
  const bool vb = (tx < 140) && (unsigned)ghb < (unsigned)H &&
                  (unsigned)gwb < (unsigned)W;
  const int offa = va ? (gha * W + gwa) : 0;      // clamped safe offset
  const int offb = vb ? (ghb * W + gwb) : 0;
  const float* xbase = x + (size_t)n * CCH * HWi;

  float acc[4][16];
#pragma unroll
  for (int a = 0; a < 4; ++a)
#pragma unroll
    for (int b = 0; b < 16; ++b) acc[a][b] = 0.f;

  float sx0[8], sx1[8];

  // ---- prologue: stage ck=0 into buffer 0
#pragma unroll
  for (int ci = 0; ci < 8; ++ci) {
    float u0 = xbase[ci * HWi + offa];
    float u1 = xbase[ci * HWi + offb];
    sx0[ci] = va ? u0 : 0.f;
    sx1[ci] = vb ? u1 : 0.f;
  }
#pragma unroll
  for (int ci = 0; ci < 8; ++ci) {
    xs[0][ci][ra][ca] = sx0[ci];
    if (tx < 140) xs[0][ci][rb][cb] = sx1[ci];
  }
  __syncthreads();

  // per-thread weight base: wT[(cin*9+tap)*256 + cout0 + cog4*4]
  const float* wbase = wT + cout0 + cog4 * 4;

#pragma unroll 2
  for (int ck = 0; ck < 32; ++ck) {
    const int cur = ck & 1;

    // ---- T14 issue-early: global loads for ck+1 (held in regs)
    if (ck < 31) {
      const float* pk = xbase + (size_t)(ck + 1) * 8 * HWi;
#pragma unroll
      for (int ci = 0; ci < 8; ++ci) {
        float u0 = pk[ci * HWi + offa];
        float u1 = pk[ci * HWi + offb];
        sx0[ci] = va ? u0 : 0.f;
        sx1[ci] = vb ? u1 : 0.f;
      }
      __builtin_amdgcn_sched_barrier(0);  // keep loads issued before compute
    }

    // ---- compute ck from xs[cur]; weights straight from L2-resident wT
    const float* wck = wbase + (size_t)ck * (72 * 256);
#pragma unroll
    for (int ci = 0; ci < 8; ++ci) {
#pragma unroll
      for (int kh = 0; kh < 3; ++kh) {
        const float* p = &xs[cur][ci][r2 + kh][col0];
        float4 a0 = *reinterpret_cast<const float4*>(p);
        float4 a1 = *reinterpret_cast<const float4*>(p + 4);
        float4 a2 = *reinterpret_cast<const float4*>(p + 8);
        float4 a3 = *reinterpret_cast<const float4*>(p + 12);
        float2 a4 = *reinterpret_cast<const float2*>(p + 16);
        // xr[i] = halo col (col0 + i); output col j, tap kw uses xr[j+kw]
        float xr[18] = {a0.x, a0.y, a0.z, a0.w, a1.x, a1.y, a1.z, a1.w,
                        a2.x, a2.y, a2.z, a2.w, a3.x, a3.y, a3.z, a3.w,
                        a4.x, a4.y};
#pragma unroll
        for (int kw = 0; kw < 3; ++kw) {
          float4 wq = *reinterpret_cast<const float4*>(
              wck + ((ci * 9 + kh * 3 + kw) << 8));
          float wv[4] = {wq.x, wq.y, wq.z, wq.w};
#pragma unroll
          for (int co = 0; co < 4; ++co)
#pragma unroll
            for (int j = 0; j < 16; ++j)
              acc[co][j] = fmaf(xr[j + kw], wv[co], acc[co][j]);
        }
      }
    }

    // ---- write-late into the other buffer, single barrier per ck
    if (ck < 31) {
#pragma unroll
      for (int ci = 0; ci < 8; ++ci) {
        xs[cur ^ 1][ci][ra][ca] = sx0[ci];
        if (tx < 140) xs[cur ^ 1][ci][rb][cb] = sx1[ci];
      }
      __syncthreads();
    }
  }

  const int h = h0 + r2;
#pragma unroll
  for (int co = 0; co < 4; ++co) {
    int c = cout0 + cog4 * 4 + co;
    float bv = bias[c];
#pragma unroll
    for (int j = 0; j < 16; ++j) {
      int ww = w0 + col0 + j;
      if (ww < W) {
        float v = acc[co][j] + bv;
        t[((size_t)(n * CCH + c) * H + h) * W + ww] = v > 0.f ? v : 0.f;
      }
    }
  }
}

// K1a: level-0 conv (H=W=256), grid (4,64,8)
__global__ __launch_bounds__(256, 3)
void k_conv0(const float* __restrict__ x, const float* __restrict__ wT,
             const float* __restrict__ bias, float* __restrict__ t) {
  int n = blockIdx.z >> 2, cog = blockIdx.z & 3;
  conv_body(x, wT, bias, t, 256, 256, n, cog, blockIdx.y * 4, blockIdx.x * 64);
}

// K1b: fused conv for levels 1-4 (736 blocks, 1D grid, block table)
__global__ __launch_bounds__(256, 3)
void k_conv4(const float* __restrict__ f1, const float* __restrict__ f2,
             const float* __restrict__ f3, const float* __restrict__ f4,
             const float* __restrict__ wT, const float* __restrict__ bias,
             float* __restrict__ t) {
  int b = blockIdx.x;
  const float* x; float* tb; int H, gx, gy, l;
  if (b < 512)      { x = f1; tb = t;            H = 128; gx = 2; gy = 32; l = b; }
  else if (b < 640) { x = f2; tb = t +  8388608; H =  64; gx = 1; gy = 16; l = b - 512; }
  else if (b < 704) { x = f3; tb = t + 10485760; H =  32; gx = 1; gy =  8; l = b - 640; }
  else              { x = f4; tb = t + 11010048; H =  16; gx = 1; gy =  4; l = b - 704; }
  int bx = l % gx;
  int by = (l / gx) % gy;
  int bz = l / (gx * gy);
  int n = bz >> 2, cog = bz & 3;
  conv_body(x, wT, bias, tb, H, H, n, cog, by * 4, bx * 64);
}

// ---------------- 1x1 heads body (4 pixels/thread, float4 loads) ----------
__device__ __forceinline__ void heads_body(
    const float* __restrict__ t,
    const float* __restrict__ wobj, const float* __restrict__ bobj,
    const float* __restrict__ wdel, const float* __restrict__ bdel,
    float* __restrict__ logits, float4* __restrict__ deltas,
    int HW, int loff, int n, int p0) {
  __shared__ float wl[15][256];
  __shared__ float bl[15];
  for (int i = threadIdx.x; i < 15 * 256; i += 256) {
    int o = i >> 8, c = i & 255;
    wl[o][c] = (o < 3) ? wobj[o * 256 + c] : wdel[(o - 3) * 256 + c];
  }
  if (threadIdx.x < 15)
    bl[threadIdx.x] = (threadIdx.x < 3) ? bobj[threadIdx.x] : bdel[threadIdx.x - 3];
  __syncthreads();
  if (p0 >= HW) return;

  float4 acc[15];
#pragma unroll
  for (int o = 0; o < 15; ++o) acc[o] = make_float4(0.f, 0.f, 0.f, 0.f);
  const float* tp = t + (size_t)n * CCH * HW + p0;
  for (int c = 0; c < 256; ++c) {
    float4 v = *reinterpret_cast<const float4*>(tp + (size_t)c * HW);
#pragma unroll
    for (int o = 0; o < 15; ++o) {
      float wv = wl[o][c];
      acc[o].x = fmaf(v.x, wv, acc[o].x);
      acc[o].y = fmaf(v.y, wv, acc[o].y);
      acc[o].z = fmaf(v.z, wv, acc[o].z);
      acc[o].w = fmaf(v.w, wv, acc[o].w);
    }
  }
#pragma unroll
  for (int o = 0; o < 15; ++o) {
    float bv = bl[o];
    acc[o].x += bv; acc[o].y += bv; acc[o].z += bv; acc[o].w += bv;
  }

  const float* af = reinterpret_cast<const float*>(acc);
  size_t base = (size_t)n * LTOT + loff + (size_t)p0 * 3;
#pragma unroll
  for (int i2 = 0; i2 < 4; ++i2) {
#pragma unroll
    for (int a = 0; a < 3; ++a) {
      logits[base + i2 * 3 + a] = af[a * 4 + i2];
      deltas[base + i2 * 3 + a] =
          make_float4(af[(3 + a * 4 + 0) * 4 + i2], af[(3 + a * 4 + 1) * 4 + i2],
                      af[(3 + a * 4 + 2) * 4 + i2], af[(3 + a * 4 + 3) * 4 + i2]);
    }
  }
}

__global__ __launch_bounds__(256)
void k_heads0(const float* __restrict__ t,
              const float* __restrict__ wobj, const float* __restrict__ bobj,
              const float* __restrict__ wdel, const float* __restrict__ bdel,
              float* __restrict__ logits, float4* __restrict__ deltas) {
  heads_body(t, wobj, bobj, wdel, bdel, logits, deltas,
             65536, 0, blockIdx.y, (blockIdx.x * 256 + threadIdx.x) * 4);
}

__global__ __launch_bounds__(256)
void k_heads4(const float* __restrict__ t,
              const float* __restrict__ wobj, const float* __restrict__ bobj,
              const float* __restrict__ wdel, const float* __restrict__ bdel,
              float* __restrict__ logits, float4* __restrict__ deltas) {
  int b = blockIdx.x;
  const float* tb; int HW, loff, start;
  if (b < 16)      { tb = t;            HW = 16384; loff = 196608; start = 0;  }
  else if (b < 20) { tb = t +  8388608; HW =  4096; loff = 245760; start = 16; }
  else if (b < 21) { tb = t + 10485760; HW =  1024; loff = 258048; start = 20; }
  else             { tb = t + 11010048; HW =   256; loff = 261120; start = 21; }
  heads_body(tb, wobj, bobj, wdel, bdel, logits, deltas,
             HW, loff, blockIdx.y, ((b - start) * 256 + threadIdx.x) * 4);
}

// ---------------- K3: per-(n,level) exact stable top-k + box decode -------
__global__ __launch_bounds__(1024)
void k_topk(const float* __restrict__ logits, const float4* __restrict__ deltas,
            float* __restrict__ scat, float4* __restrict__ bout,
            double* __restrict__ obout, unsigned* __restrict__ valid) {
  constexpr int   Hs[5]    = {256, 128, 64, 32, 16};
  constexpr int   strd[5]  = {4, 8, 16, 32, 64};
  constexpr float szs[5]   = {32.f, 64.f, 128.f, 256.f, 512.f};
  constexpr int   loffs[5] = {0, 196608, 245760, 258048, 261120};
  constexpr int   Ms[5]    = {196608, 49152, 12288, 3072, 768};
  constexpr int   ksz[5]   = {1000, 1000, 1000, 1000, 768};
  constexpr int   coffs[5] = {0, 1000, 2000, 3000, 4000};

  __shared__ unsigned hist[2048];
  __shared__ unsigned long long cand[1024];
  __shared__ unsigned tie[1024];
  __shared__ unsigned sB1, sC1, sB2, sC2, sDK, sTN;
  __shared__ unsigned cntG, cntT;

  const int task = blockIdx.x;
  const int n = task / 5, lvl = task % 5;
  const int M = Ms[lvl], K = ksz[lvl], loff = loffs[lvl];
  const float* lg = logits + (size_t)n * LTOT + loff;
  const int tid = threadIdx.x;

  for (int i = tid; i < 2048; i += 1024) hist[i] = 0;
  if (tid == 0) { cntG = 0; cntT = 0; }
  __syncthreads();
  for (int i = tid; i < M; i += 1024) atomicAdd(&hist[keyd(lg[i]) >> 21], 1u);
  __syncthreads();
  if (tid == 0) {
    unsigned acc = 0;
    for (int b = 2047; b >= 0; --b) {
      unsigned na = acc + hist[b];
      if (na >= (unsigned)K) { sB1 = (unsigned)b; sC1 = acc; break; }
      acc = na;
    }
  }
  __syncthreads();
  const unsigned B1 = sB1;
  const unsigned rem1 = (unsigned)K - sC1;

  for (int i = tid; i < 2048; i += 1024) hist[i] = 0;
  __syncthreads();
  for (int i = tid; i < M; i += 1024) {
    unsigned d = keyd(lg[i]);
    if ((d >> 21) == B1) atomicAdd(&hist[(d >> 10) & 0x7FFu], 1u);
  }
  __syncthreads();
  if (tid == 0) {
    unsigned acc = 0;
    for (int b = 2047; b >= 0; --b) {
      unsigned na = acc + hist[b];
      if (na >= rem1) { sB2 = (unsigned)b; sC2 = acc; break; }
      acc = na;
    }
  }
  __syncthreads();
  const unsigned B2 = sB2;
  const unsigned rem2 = rem1 - sC2;
  const unsigned pfx = (B1 << 11) | B2;

  for (int i = tid; i < 1024; i += 1024) hist[i] = 0;
  __syncthreads();
  for (int i = tid; i < M; i += 1024) {
    unsigned d = keyd(lg[i]);
    if ((d >> 10) == pfx) atomicAdd(&hist[d & 0x3FFu], 1u);
  }
  __syncthreads();
  if (tid == 0) {
    unsigned acc = 0;
    for (int b = 1023; b >= 0; --b) {
      unsigned na = acc + hist[b];
      if (na >= rem2) { sDK = (pfx << 10) | (unsigned)b; sTN = rem2 - acc; break; }
      acc = na;
    }
  }
  __syncthreads();
  const unsigned dk = sDK;
  const unsigned tneed = sTN;
  const unsigned cg = (unsigned)K - tneed;

  for (int i = tid; i < M; i += 1024) {
    unsigned d = keyd(lg[i]);
    if (d > dk) {
      unsigned p = atomicAdd(&cntG, 1u);
      cand[p] = ((unsigned long long)(~d) << 32) | (unsigned)i;
    } else if (d == dk) {
      unsigned q = atomicAdd(&cntT, 1u);
      if (q < 1024u) tie[q] = (unsigned)i;
    }
  }
  __syncthreads();
  if (tid == 0) {
    int ct = (int)(cntT < 1024u ? cntT : 1024u);
    for (int a = 1; a < ct; ++a) {
      unsigned v = tie[a]; int b = a - 1;
      while (b >= 0 && tie[b] > v) { tie[b + 1] = tie[b]; --b; }
      tie[b + 1] = v;
    }
    for (unsigned q = 0; q < tneed; ++q)
      cand[cg + q] = ((unsigned long long)(~dk) << 32) | tie[q];
  }
  __syncthreads();
  if (tid >= K) cand[tid] = ~0ULL;
  __syncthreads();

  for (unsigned k2 = 2; k2 <= 1024; k2 <<= 1)
    for (unsigned j = k2 >> 1; j > 0; j >>= 1) {
      __syncthreads();
      unsigned i = (unsigned)tid, l = i ^ j;
      if (l > i) {
        unsigned long long a = cand[i], b = cand[l];
        bool up = ((i & k2) == 0);
        if (up ? (a > b) : (a < b)) { cand[i] = b; cand[l] = a; }
      }
    }
  __syncthreads();

  if (tid < K) {
    unsigned long long kk = cand[tid];
    unsigned idx = (unsigned)kk;
    unsigned d = ~(unsigned)(kk >> 32);
    float s = invkey(d);
    int catpos = n * MCAT + coffs[lvl] + tid;
    scat[catpos] = s;

    int a = idx % 3;
    int pix = idx / 3;
    int W = Hs[lvl];
    int hh = pix / W;
    int ww = pix - hh * W;
    float4 d4 = deltas[(size_t)n * LTOT + loff + idx];

    double r  = (a == 0) ? 0.5 : (a == 1 ? 1.0 : 2.0);
    double sz = (double)szs[lvl];
    double cw = sz / sqrt(r);
    double ch = cw * r;
    double cx = (double)(ww * strd[lvl]);
    double cy = (double)(hh * strd[lvl]);
    double dx = (double)d4.x, dy = (double)d4.y;
    double dw = (double)d4.z; if (dw > SCALE_CLAMP_D) dw = SCALE_CLAMP_D;
    double dh = (double)d4.w; if (dh > SCALE_CLAMP_D) dh = SCALE_CLAMP_D;
    double pcx = dx * cw + cx, pcy = dy * ch + cy;
    double pw = exp(dw) * cw,  ph = exp(dh) * ch;
    double x0 = pcx - 0.5 * pw, y0 = pcy - 0.5 * ph;
    double x1 = pcx + 0.5 * pw, y1 = pcy + 0.5 * ph;
    x0 = x0 < 0.0 ? 0.0 : (x0 > 1024.0 ? 1024.0 : x0);
    y0 = y0 < 0.0 ? 0.0 : (y0 > 1024.0 ? 1024.0 : y0);
    x1 = x1 < 0.0 ? 0.0 : (x1 > 1024.0 ? 1024.0 : x1);
    y1 = y1 < 0.0 ? 0.0 : (y1 > 1024.0 ? 1024.0 : y1);
    bool vld = ((x1 - x0) > 0.0) && ((y1 - y0) > 0.0);

    bout[catpos] = make_float4((float)x0, (float)y0, (float)x1, (float)y1);
    double off = (double)lvl * 4096.0;
    double* op = obout + (size_t)catpos * 4;
    op[0] = x0 + off; op[1] = y0 + off; op[2] = x1 + off; op[3] = y1 + off;
    valid[catpos] = vld ? 1u : 0u;
  }
}

// ---------------- K4: per-image stable sort of 4768 candidates ------------
__global__ __launch_bounds__(1024)
void k_sort(const float* __restrict__ scat, const float4* __restrict__ b,
            const double* __restrict__ ob, const unsigned* __restrict__ valid,
            float* __restrict__ s_s, float4* __restrict__ b_s,
            double* __restrict__ ob_s, unsigned* __restrict__ valid_s) {
  __shared__ unsigned long long sk[8192];
  const int n = blockIdx.x;
  const int tid = threadIdx.x;
  for (int i = tid; i < 8192; i += 1024)
    sk[i] = (i < MCAT)
      ? ((unsigned long long)(~keyd(scat[n * MCAT + i])) << 32) | (unsigned)i
      : ~0ULL;
  __syncthreads();
  for (unsigned k2 = 2; k2 <= 8192; k2 <<= 1)
    for (unsigned j = k2 >> 1; j > 0; j >>= 1) {
      for (int m = 0; m < 8; ++m) {
        unsigned i = (unsigned)tid + (unsigned)m * 1024u;
        unsigned l = i ^ j;
        if (l > i) {
          unsigned long long a = sk[i], bb = sk[l];
          bool up = ((i & k2) == 0);
          if (up ? (a > bb) : (a < bb)) { sk[i] = bb; sk[l] = a; }
        }
      }
      __syncthreads();
    }
  for (int r = tid; r < MCAT; r += 1024) {
    unsigned long long kk = sk[r];
    unsigned pos = (unsigned)kk;
    unsigned d = ~(unsigned)(kk >> 32);
    s_s[n * MCAT + r] = invkey(d);
    b_s[n * MCAT + r] = b[n * MCAT + pos];
    const double* src = ob + ((size_t)n * MCAT + pos) * 4;
    double* dst = ob_s + ((size_t)n * MCAT + r) * 4;
    dst[0] = src[0]; dst[1] = src[1]; dst[2] = src[2]; dst[3] = src[3];
    valid_s[n * MCAT + r] = valid[n * MCAT + pos];
  }
}

// ---------------- K5: suppression bitmask (fp64 IoU, j>i bits) ------------
__global__ __launch_bounds__(256)
void k_mask(const double* __restrict__ ob_s, unsigned long long* __restrict__ mask) {
  const int n = blockIdx.y;
  const int i = blockIdx.x;
  const double* bi = ob_s + ((size_t)n * MCAT + i) * 4;
  const double ix0 = bi[0], iy0 = bi[1], ix1 = bi[2], iy1 = bi[3];
  const double ai = (ix1 - ix0) * (iy1 - iy0);
  const int tid = threadIdx.x;
  for (int j0 = 0; j0 < MCAT; j0 += 256) {
    int j = j0 + tid;
    bool sup = false;
    if (j < MCAT && j > i) {
      const double* bj = ob_s + ((size_t)n * MCAT + j) * 4;
      double jx0 = bj[0], jy0 = bj[1], jx1 = bj[2], jy1 = bj[3];
      double aj = (jx1 - jx0) * (jy1 - jy0);
      double lx = ix0 > jx0 ? ix0 : jx0;
      double ly = iy0 > jy0 ? iy0 : jy0;
      double rx = ix1 < jx1 ? ix1 : jx1;
      double ry = iy1 < jy1 ? iy1 : jy1;
      double wx = rx - lx; wx = wx > 0.0 ? wx : 0.0;
      double wy = ry - ly; wy = wy > 0.0 ? wy : 0.0;
      double inter = wx * wy;
      double iou = inter / (ai + aj - inter + 1e-9);
      sup = iou > 0.7;
    }
    unsigned long long bal = __ballot(sup);
    if ((tid & 63) == 0) {
      int word = (j0 + tid) >> 6;
      if (word < MW) mask[((size_t)n * MCAT + i) * MW + word] = bal;
    }
  }
}

// ---------------- K6: greedy NMS scan (parallel rem-update) + output ------
__global__ __launch_bounds__(256)
void k_nms(const unsigned long long* __restrict__ mask,
           const unsigned* __restrict__ valid_s,
           const float* __restrict__ s_s, const float4* __restrict__ b_s,
           float* __restrict__ out) {
  __shared__ unsigned long long rem[MW];
  __shared__ unsigned long long supcc[64];
  __shared__ unsigned long long keepw[MW];
  __shared__ int kl[64];
  __shared__ int snk;
  __shared__ unsigned kpfx[MW], nkpfx[MW];
  __shared__ unsigned sKept;
  const int n = blockIdx.x;
  const int tid = threadIdx.x;
  const unsigned long long* msk = mask + (size_t)n * MCAT * MW;

  for (int w = tid; w < MW; w += 256) {
    unsigned long long r = 0ULL;
    for (int b = 0; b < 64; ++b) {
      int i = w * 64 + b;
      bool rm = (i >= MCAT) || (valid_s[n * MCAT + i] == 0u);
      if (rm) r |= (1ULL << b);
    }
    rem[w] = r;
    keepw[w] = 0ULL;
  }
  __syncthreads();

  for (int c = 0; c < MW; ++c) {
    if (tid < 64) {
      int i = c * 64 + tid;
      supcc[tid] = (i < MCAT) ? msk[(size_t)i * MW + c] : 0ULL;
    }
    __syncthreads();
    if (tid == 0) {
      unsigned long long r = rem[c], km = 0ULL;
      int nk = 0;
      for (int b = 0; b < 64; ++b) {
        if (!((r >> b) & 1ULL)) { km |= (1ULL << b); kl[nk++] = b; r |= supcc[b]; }
      }
      rem[c] = r; keepw[c] = km; snk = nk;
    }
    __syncthreads();
    const int nk = snk;
    const int nw = MW - 1 - c;
    const int total = nk * nw;
    for (int idx = tid; idx < total; idx += 256) {
      int b = kl[idx / nw];
      int w = c + 1 + (idx % nw);
      unsigned long long v = msk[(size_t)(c * 64 + b) * MW + w];
      if (v) atomicOr(&rem[w], v);
    }
    __syncthreads();
  }

  if (tid == 0) {
    unsigned ka = 0, na = 0;
    for (int w = 0; w < MW; ++w) {
      kpfx[w] = ka; nkpfx[w] = na;
      unsigned long long range = (w < MW - 1) ? ~0ULL : ((1ULL << 32) - 1ULL);
      ka += (unsigned)__popcll(keepw[w]);
      na += (unsigned)__popcll((~keepw[w]) & range);
    }
    sKept = ka;
  }
  __syncthreads();
  const unsigned keptTotal = sKept;

  for (int i = tid; i < MCAT; i += 256) {
    int w = i >> 6, b = i & 63;
    unsigned long long below = (1ULL << b) - 1ULL;
    bool kept = (keepw[w] >> b) & 1ULL;
    unsigned row;
    if (kept)
      row = kpfx[w] + (unsigned)__popcll(keepw[w] & below);
    else
      row = keptTotal + nkpfx[w] + (unsigned)__popcll((~keepw[w]) & below);
    if (row < 1000u) {
      float4 bb = b_s[n * MCAT + i];
      float sc = kept ? s_s[n * MCAT + i] : -1e4f;
      float* o = out + ((size_t)n * 1000 + row) * 5;
      o[0] = bb.x; o[1] = bb.y; o[2] = bb.z; o[3] = bb.w; o[4] = sc;
    }
  }
}

// ---------------- launch ----------------
extern "C" void kernel_launch(void* const* d_in, const int* in_sizes, int n_in,
                              void* d_out, int out_size, void* d_ws, size_t ws_size,
                              hipStream_t stream) {
  (void)in_sizes; (void)n_in; (void)out_size;
  const float* feats[5] = {(const float*)d_in[0], (const float*)d_in[1],
                           (const float*)d_in[2], (const float*)d_in[3],
                           (const float*)d_in[4]};
  const float* w_conv = (const float*)d_in[5];
  const float* b_conv = (const float*)d_in[6];
  const float* w_obj  = (const float*)d_in[7];
  const float* b_obj  = (const float*)d_in[8];
  const float* w_del  = (const float*)d_in[9];
  const float* b_del  = (const float*)d_in[10];
  float* out = (float*)d_out;

  char* p = (char*)d_ws;
  auto alloc = [&](size_t bytes) -> void* {
    void* r = (void*)p;
    p += (bytes + 255) & ~(size_t)255;
    return r;
  };
  float*  t       = (float*)  alloc((size_t)2 * 256 * 256 * 256 * 4); // 134 MB, lvl1-4 then lvl0
  float*  wT      = (float*)  alloc((size_t)2304 * 256 * 4);
  float*  logits  = (float*)  alloc((size_t)NIMG * LTOT * 4);
  float4* deltas  = (float4*) alloc((size_t)NIMG * LTOT * 16);
  float*  scat    = (float*)  alloc((size_t)NIMG * MCAT * 4);
  float4* bout    = (float4*) alloc((size_t)NIMG * MCAT * 16);
  double* obout   = (double*) alloc((size_t)NIMG * MCAT * 32);
  unsigned* valid = (unsigned*)alloc((size_t)NIMG * MCAT * 4);
  float*  s_s     = (float*)  alloc((size_t)NIMG * MCAT * 4);
  float4* b_s     = (float4*) alloc((size_t)NIMG * MCAT * 16);
  double* ob_s    = (double*) alloc((size_t)NIMG * MCAT * 32);
  unsigned* val_s = (unsigned*)alloc((size_t)NIMG * MCAT * 4);
  unsigned long long* mask =
      (unsigned long long*)alloc((size_t)NIMG * MCAT * MW * 8);
  if ((size_t)(p - (char*)d_ws) > ws_size) return;

  k_wT<<<2304, 256, 0, stream>>>(w_conv, wT);

  // levels 1-4 fused (t[0..11141120)), heads4 consumes, then level 0 reuses t
  k_conv4<<<736, 256, 0, stream>>>(feats[1], feats[2], feats[3], feats[4],
                                   wT, b_conv, t);
  k_heads4<<<dim3(22, 2), 256, 0, stream>>>(t, w_obj, b_obj, w_del, b_del,
                                            logits, deltas);
  k_conv0<<<dim3(4, 64, 8), 256, 0, stream>>>(feats[0], wT, b_conv, t);
  k_heads0<<<dim3(64, 2), 256, 0, stream>>>(t, w_obj, b_obj, w_del, b_del,
                                            logits, deltas);

  k_topk<<<10, 1024, 0, stream>>>(logits, deltas, scat, bout, obout, valid);
  k_sort<<<2, 1024, 0, stream>>>(scat, bout, obout, valid, s_s, b_s, ob_s, val_s);
  k_mask<<<dim3(MCAT, 2), 256, 0, stream>>>(ob_s, mask);
  k_nms<<<2, 256, 0, stream>>>(mask, val_s, s_s, b_s, out);
}

// Round 2
// 4767.721 us; speedup vs baseline: 6.4624x; 6.4624x over previous
//
#include <hip/hip_runtime.h>
#include <cstdint>
#include <cstddef>

// ---------------- constants ----------------
static constexpr int NIMG = 2;
static constexpr int CCH  = 256;                  // channels
static constexpr int LTOT = 261888;               // sum H*W*3 over levels
static constexpr int MCAT = 4768;                 // 1000*4 + 768
static constexpr int MW   = 75;                   // ceil(4768/64)
static constexpr double SCALE_CLAMP_D = 4.135166556742356; // ln(1000/16)

// BITWISE CONSTRAINT: the harness np-reference is fp32 and our conv matched
// bitwise (absmax exactly 0.0). Sorted-score spacing (~7.7e-4) makes any
// logit error >~1e-7 flip ranks -> huge absmax. The conv MUST remain
// sequential fp32 FMA in (cin ascending, kh, kw) order per output element.
// No MFMA, no K-splitting, no reassociation. Thread->output mapping is free.
//
// R1 post-mortem: holding staged values in regs across the 4608-FMA compute
// + unroll-2 + sched_barrier spilled xr/staging to scratch (WRITE_SIZE 46GB).
// R2: double-buffered LDS (xs AND wsm), stage ck+1 with global->reg->ds_write
// IMMEDIATELY (no cross-compute liveness, same dataflow as R0), ONE barrier
// per ck. Stage-first ordering: a wave's load latency overlaps other waves'
// compute (no barrier between phases). xs row stride 76->68 to fit 64KB
// static LDS (row starts still 16B-aligned, bank starts still 0,4,..,28).
// FMA order unchanged -> bitwise-identical output.

// ---------------- key helpers (descending-order monotone uint key) --------
__device__ __forceinline__ unsigned keyd(float f) {
  unsigned u = __float_as_uint(f);
  return (u >> 31) ? ~u : (u | 0x80000000u);
}
__device__ __forceinline__ float invkey(unsigned d) {
  unsigned u = (d & 0x80000000u) ? (d & 0x7FFFFFFFu) : ~d;
  return __uint_as_float(u);
}

// ---------------- K0: transpose conv weights [O][I][3][3] -> [I*9][O] -----
__global__ void k_wT(const float* __restrict__ w, float* __restrict__ wT) {
  int i = blockIdx.x * 256 + threadIdx.x;
  if (i >= 2304 * 256) return;
  int co = i & 255;
  int ct = i >> 8;                 // ci*9 + tap
  wT[ct * 256 + co] = w[co * 2304 + ct];
}

// ---------------- conv3x3 + bias + relu (fp32, bitwise-pinned) ------------
// Block tile: 64 couts x (4 rows x 64 cols). 256 threads, each 4co x 16px.
__device__ __forceinline__ void conv_body(
    const float* __restrict__ x, const float* __restrict__ wT,
    const float* __restrict__ bias, float* __restrict__ t,
    int H, int W, int n, int cog, int h0, int w0) {
  // double-buffered tiles: one barrier per ck.
  // xs: 6 halo rows x 66 halo cols, stride 68 (16B-aligned rows; bank starts
  // (68*r2+16*c)%32 = {0,4,8,...,28} -> perfect 2-lane/bank spread).
  __shared__ __align__(16) float xs[2][8][6][68];    // 26112 B
  __shared__ __align__(16) float wsm[2][8][9][64];   // 36864 B

  const int cout0 = cog * 64;
  const int tx = threadIdx.x;
  const int cog4 = tx >> 4;        // 0..15 -> couts cout0+cog4*4 ..+3
  const int pxg  = tx & 15;
  const int r2   = pxg >> 2;       // row 0..3
  const int col0 = (pxg & 3) * 16; // col group (16 px per thread)
  const int HWi  = H * W;

  // ---- ck-invariant x-staging geometry: elems {tx, tx+256} of 396 = 6*66
  const int ra = tx / 66, ca = tx - ra * 66;
  const int e1 = tx + 256;
  const int rb = e1 / 66, cb = e1 - rb * 66;      // used only when tx < 140
  const int gha = h0 - 1 + ra, gwa = w0 - 1 + ca;
  const int ghb = h0 - 1 + rb, gwb = w0 - 1 + cb;
  const bool va = (unsigned)gha < (unsigned)H && (unsigned)gwa < (unsigned)W;
  const bool vb = (tx < 140) && (unsigned)ghb < (unsigned)H &&
                  (unsigned)gwb < (unsigned)W;
  const int offa = va ? (gha * W + gwa) : 0;      // clamped safe offset
  const int offb = vb ? (ghb * W + gwb) : 0;
  const float* xb = x + (size_t)n * CCH * HWi;

  // ---- ck-invariant w-staging geometry: elems {tx, tx+256, tx+512} of 576
  const int tapA = tx >> 6, coA = tx & 63;        // taps 0..3
  // e=tx+256 -> tap 4+tapA, same co; e=tx+512 (tx<64) -> tap 8, co=tx

  // stage (global -> reg -> ds_write immediately; nothing held across compute)
  auto stage = [&](int ck, int bi) {
    const float* xk = xb + (size_t)ck * 8 * HWi;
#pragma unroll
    for (int ci = 0; ci < 8; ++ci) {
      const float* xc = xk + ci * HWi;
      float u0 = xc[offa];
      xs[bi][ci][ra][ca] = va ? u0 : 0.f;
      if (tx < 140) {
        float u1 = xc[offb];
        xs[bi][ci][rb][cb] = vb ? u1 : 0.f;
      }
    }
    const float* wk = wT + (size_t)(ck * 8) * 9 * 256 + cout0;
#pragma unroll
    for (int ci = 0; ci < 8; ++ci) {
      const float* wc = wk + (size_t)ci * 9 * 256;
      wsm[bi][ci][tapA][coA]     = wc[tapA * 256 + coA];
      wsm[bi][ci][4 + tapA][coA] = wc[(4 + tapA) * 256 + coA];
      if (tx < 64) wsm[bi][ci][8][tx] = wc[8 * 256 + tx];
    }
  };

  float acc[4][16];
#pragma unroll
  for (int a = 0; a < 4; ++a)
#pragma unroll
    for (int b = 0; b < 16; ++b) acc[a][b] = 0.f;

  stage(0, 0);
  __syncthreads();

  for (int ck = 0; ck < 32; ++ck) {
    const int cur = ck & 1;
    // ---- stage next ck into the other buffer (no barrier before compute:
    // this wave's load-wait overlaps other waves' FMA work)
    if (ck < 31) stage(ck + 1, cur ^ 1);

    // ---- compute ck from buffer cur
#pragma unroll
    for (int ci = 0; ci < 8; ++ci) {
#pragma unroll
      for (int kh = 0; kh < 3; ++kh) {
        const float* p = &xs[cur][ci][r2 + kh][col0];
        float4 a0 = *reinterpret_cast<const float4*>(p);
        float4 a1 = *reinterpret_cast<const float4*>(p + 4);
        float4 a2 = *reinterpret_cast<const float4*>(p + 8);
        float4 a3 = *reinterpret_cast<const float4*>(p + 12);
        float2 a4 = *reinterpret_cast<const float2*>(p + 16);
        // xr[i] = halo col (col0 + i); output col j, tap kw uses xr[j+kw]
        float xr[18] = {a0.x, a0.y, a0.z, a0.w, a1.x, a1.y, a1.z, a1.w,
                        a2.x, a2.y, a2.z, a2.w, a3.x, a3.y, a3.z, a3.w,
                        a4.x, a4.y};
#pragma unroll
        for (int kw = 0; kw < 3; ++kw) {
          float4 wq = *reinterpret_cast<const float4*>(
              &wsm[cur][ci][kh * 3 + kw][cog4 * 4]);
          float wv[4] = {wq.x, wq.y, wq.z, wq.w};
#pragma unroll
          for (int co = 0; co < 4; ++co)
#pragma unroll
            for (int j = 0; j < 16; ++j)
              acc[co][j] = fmaf(xr[j + kw], wv[co], acc[co][j]);
        }
      }
    }
    __syncthreads();   // buf^1 complete for next iter; cur free to overwrite
  }

  const int h = h0 + r2;
#pragma unroll
  for (int co = 0; co < 4; ++co) {
    int c = cout0 + cog4 * 4 + co;
    float bv = bias[c];
#pragma unroll
    for (int j = 0; j < 16; ++j) {
      int ww = w0 + col0 + j;
      if (ww < W) {
        float v = acc[co][j] + bv;
        t[((size_t)(n * CCH + c) * H + h) * W + ww] = v > 0.f ? v : 0.f;
      }
    }
  }
}

// K1a: level-0 conv (H=W=256), grid (4,64,8). LDS 63KB -> 2 blocks/CU.
__global__ __launch_bounds__(256, 2)
void k_conv0(const float* __restrict__ x, const float* __restrict__ wT,
             const float* __restrict__ bias, float* __restrict__ t) {
  int n = blockIdx.z >> 2, cog = blockIdx.z & 3;
  conv_body(x, wT, bias, t, 256, 256, n, cog, blockIdx.y * 4, blockIdx.x * 64);
}

// K1b: fused conv for levels 1-4 (736 blocks, 1D grid, block table)
__global__ __launch_bounds__(256, 2)
void k_conv4(const float* __restrict__ f1, const float* __restrict__ f2,
             const float* __restrict__ f3, const float* __restrict__ f4,
             const float* __restrict__ wT, const float* __restrict__ bias,
             float* __restrict__ t) {
  int b = blockIdx.x;
  const float* x; float* tb; int H, gx, gy, l;
  if (b < 512)      { x = f1; tb = t;            H = 128; gx = 2; gy = 32; l = b; }
  else if (b < 640) { x = f2; tb = t +  8388608; H =  64; gx = 1; gy = 16; l = b - 512; }
  else if (b < 704) { x = f3; tb = t + 10485760; H =  32; gx = 1; gy =  8; l = b - 640; }
  else              { x = f4; tb = t + 11010048; H =  16; gx = 1; gy =  4; l = b - 704; }
  int bx = l % gx;
  int by = (l / gx) % gy;
  int bz = l / (gx * gy);
  int n = bz >> 2, cog = bz & 3;
  conv_body(x, wT, bias, tb, H, H, n, cog, by * 4, bx * 64);
}

// ---------------- 1x1 heads body (4 pixels/thread, float4 loads) ----------
__device__ __forceinline__ void heads_body(
    const float* __restrict__ t,
    const float* __restrict__ wobj, const float* __restrict__ bobj,
    const float* __restrict__ wdel, const float* __restrict__ bdel,
    float* __restrict__ logits, float4* __restrict__ deltas,
    int HW, int loff, int n, int p0) {
  __shared__ float wl[15][256];
  __shared__ float bl[15];
  for (int i = threadIdx.x; i < 15 * 256; i += 256) {
    int o = i >> 8, c = i & 255;
    wl[o][c] = (o < 3) ? wobj[o * 256 + c] : wdel[(o - 3) * 256 + c];
  }
  if (threadIdx.x < 15)
    bl[threadIdx.x] = (threadIdx.x < 3) ? bobj[threadIdx.x] : bdel[threadIdx.x - 3];
  __syncthreads();
  if (p0 >= HW) return;

  float4 acc[15];
#pragma unroll
  for (int o = 0; o < 15; ++o) acc[o] = make_float4(0.f, 0.f, 0.f, 0.f);
  const float* tp = t + (size_t)n * CCH * HW + p0;
  for (int c = 0; c < 256; ++c) {
    float4 v = *reinterpret_cast<const float4*>(tp + (size_t)c * HW);
#pragma unroll
    for (int o = 0; o < 15; ++o) {
      float wv = wl[o][c];
      acc[o].x = fmaf(v.x, wv, acc[o].x);
      acc[o].y = fmaf(v.y, wv, acc[o].y);
      acc[o].z = fmaf(v.z, wv, acc[o].z);
      acc[o].w = fmaf(v.w, wv, acc[o].w);
    }
  }
#pragma unroll
  for (int o = 0; o < 15; ++o) {
    float bv = bl[o];
    acc[o].x += bv; acc[o].y += bv; acc[o].z += bv; acc[o].w += bv;
  }

  const float* af = reinterpret_cast<const float*>(acc);
  size_t base = (size_t)n * LTOT + loff + (size_t)p0 * 3;
#pragma unroll
  for (int i2 = 0; i2 < 4; ++i2) {
#pragma unroll
    for (int a = 0; a < 3; ++a) {
      logits[base + i2 * 3 + a] = af[a * 4 + i2];
      deltas[base + i2 * 3 + a] =
          make_float4(af[(3 + a * 4 + 0) * 4 + i2], af[(3 + a * 4 + 1) * 4 + i2],
                      af[(3 + a * 4 + 2) * 4 + i2], af[(3 + a * 4 + 3) * 4 + i2]);
    }
  }
}

__global__ __launch_bounds__(256)
void k_heads0(const float* __restrict__ t,
              const float* __restrict__ wobj, const float* __restrict__ bobj,
              const float* __restrict__ wdel, const float* __restrict__ bdel,
              float* __restrict__ logits, float4* __restrict__ deltas) {
  heads_body(t, wobj, bobj, wdel, bdel, logits, deltas,
             65536, 0, blockIdx.y, (blockIdx.x * 256 + threadIdx.x) * 4);
}

__global__ __launch_bounds__(256)
void k_heads4(const float* __restrict__ t,
              const float* __restrict__ wobj, const float* __restrict__ bobj,
              const float* __restrict__ wdel, const float* __restrict__ bdel,
              float* __restrict__ logits, float4* __restrict__ deltas) {
  int b = blockIdx.x;
  const float* tb; int HW, loff, start;
  if (b < 16)      { tb = t;            HW = 16384; loff = 196608; start = 0;  }
  else if (b < 20) { tb = t +  8388608; HW =  4096; loff = 245760; start = 16; }
  else if (b < 21) { tb = t + 10485760; HW =  1024; loff = 258048; start = 20; }
  else             { tb = t + 11010048; HW =   256; loff = 261120; start = 21; }
  heads_body(tb, wobj, bobj, wdel, bdel, logits, deltas,
             HW, loff, blockIdx.y, ((b - start) * 256 + threadIdx.x) * 4);
}

// ---------------- K3: per-(n,level) exact stable top-k + box decode -------
__global__ __launch_bounds__(1024)
void k_topk(const float* __restrict__ logits, const float4* __restrict__ deltas,
            float* __restrict__ scat, float4* __restrict__ bout,
            double* __restrict__ obout, unsigned* __restrict__ valid) {
  constexpr int   Hs[5]    = {256, 128, 64, 32, 16};
  constexpr int   strd[5]  = {4, 8, 16, 32, 64};
  constexpr float szs[5]   = {32.f, 64.f, 128.f, 256.f, 512.f};
  constexpr int   loffs[5] = {0, 196608, 245760, 258048, 261120};
  constexpr int   Ms[5]    = {196608, 49152, 12288, 3072, 768};
  constexpr int   ksz[5]   = {1000, 1000, 1000, 1000, 768};
  constexpr int   coffs[5] = {0, 1000, 2000, 3000, 4000};

  __shared__ unsigned hist[2048];
  __shared__ unsigned long long cand[1024];
  __shared__ unsigned tie[1024];
  __shared__ unsigned sB1, sC1, sB2, sC2, sDK, sTN;
  __shared__ unsigned cntG, cntT;

  const int task = blockIdx.x;
  const int n = task / 5, lvl = task % 5;
  const int M = Ms[lvl], K = ksz[lvl], loff = loffs[lvl];
  const float* lg = logits + (size_t)n * LTOT + loff;
  const int tid = threadIdx.x;

  for (int i = tid; i < 2048; i += 1024) hist[i] = 0;
  if (tid == 0) { cntG = 0; cntT = 0; }
  __syncthreads();
  for (int i = tid; i < M; i += 1024) atomicAdd(&hist[keyd(lg[i]) >> 21], 1u);
  __syncthreads();
  if (tid == 0) {
    unsigned acc = 0;
    for (int b = 2047; b >= 0; --b) {
      unsigned na = acc + hist[b];
      if (na >= (unsigned)K) { sB1 = (unsigned)b; sC1 = acc; break; }
      acc = na;
    }
  }
  __syncthreads();
  const unsigned B1 = sB1;
  const unsigned rem1 = (unsigned)K - sC1;

  for (int i = tid; i < 2048; i += 1024) hist[i] = 0;
  __syncthreads();
  for (int i = tid; i < M; i += 1024) {
    unsigned d = keyd(lg[i]);
    if ((d >> 21) == B1) atomicAdd(&hist[(d >> 10) & 0x7FFu], 1u);
  }
  __syncthreads();
  if (tid == 0) {
    unsigned acc = 0;
    for (int b = 2047; b >= 0; --b) {
      unsigned na = acc + hist[b];
      if (na >= rem1) { sB2 = (unsigned)b; sC2 = acc; break; }
      acc = na;
    }
  }
  __syncthreads();
  const unsigned B2 = sB2;
  const unsigned rem2 = rem1 - sC2;
  const unsigned pfx = (B1 << 11) | B2;

  for (int i = tid; i < 1024; i += 1024) hist[i] = 0;
  __syncthreads();
  for (int i = tid; i < M; i += 1024) {
    unsigned d = keyd(lg[i]);
    if ((d >> 10) == pfx) atomicAdd(&hist[d & 0x3FFu], 1u);
  }
  __syncthreads();
  if (tid == 0) {
    unsigned acc = 0;
    for (int b = 1023; b >= 0; --b) {
      unsigned na = acc + hist[b];
      if (na >= rem2) { sDK = (pfx << 10) | (unsigned)b; sTN = rem2 - acc; break; }
      acc = na;
    }
  }
  __syncthreads();
  const unsigned dk = sDK;
  const unsigned tneed = sTN;
  const unsigned cg = (unsigned)K - tneed;

  for (int i = tid; i < M; i += 1024) {
    unsigned d = keyd(lg[i]);
    if (d > dk) {
      unsigned p = atomicAdd(&cntG, 1u);
      cand[p] = ((unsigned long long)(~d) << 32) | (unsigned)i;
    } else if (d == dk) {
      unsigned q = atomicAdd(&cntT, 1u);
      if (q < 1024u) tie[q] = (unsigned)i;
    }
  }
  __syncthreads();
  if (tid == 0) {
    int ct = (int)(cntT < 1024u ? cntT : 1024u);
    for (int a = 1; a < ct; ++a) {
      unsigned v = tie[a]; int b = a - 1;
      while (b >= 0 && tie[b] > v) { tie[b + 1] = tie[b]; --b; }
      tie[b + 1] = v;
    }
    for (unsigned q = 0; q < tneed; ++q)
      cand[cg + q] = ((unsigned long long)(~dk) << 32) | tie[q];
  }
  __syncthreads();
  if (tid >= K) cand[tid] = ~0ULL;
  __syncthreads();

  for (unsigned k2 = 2; k2 <= 1024; k2 <<= 1)
    for (unsigned j = k2 >> 1; j > 0; j >>= 1) {
      __syncthreads();
      unsigned i = (unsigned)tid, l = i ^ j;
      if (l > i) {
        unsigned long long a = cand[i], b = cand[l];
        bool up = ((i & k2) == 0);
        if (up ? (a > b) : (a < b)) { cand[i] = b; cand[l] = a; }
      }
    }
  __syncthreads();

  if (tid < K) {
    unsigned long long kk = cand[tid];
    unsigned idx = (unsigned)kk;
    unsigned d = ~(unsigned)(kk >> 32);
    float s = invkey(d);
    int catpos = n * MCAT + coffs[lvl] + tid;
    scat[catpos] = s;

    int a = idx % 3;
    int pix = idx / 3;
    int W = Hs[lvl];
    int hh = pix / W;
    int ww = pix - hh * W;
    float4 d4 = deltas[(size_t)n * LTOT + loff + idx];

    double r  = (a == 0) ? 0.5 : (a == 1 ? 1.0 : 2.0);
    double sz = (double)szs[lvl];
    double cw = sz / sqrt(r);
    double ch = cw * r;
    double cx = (double)(ww * strd[lvl]);
    double cy = (double)(hh * strd[lvl]);
    double dx = (double)d4.x, dy = (double)d4.y;
    double dw = (double)d4.z; if (dw > SCALE_CLAMP_D) dw = SCALE_CLAMP_D;
    double dh = (double)d4.w; if (dh > SCALE_CLAMP_D) dh = SCALE_CLAMP_D;
    double pcx = dx * cw + cx, pcy = dy * ch + cy;
    double pw = exp(dw) * cw,  ph = exp(dh) * ch;
    double x0 = pcx - 0.5 * pw, y0 = pcy - 0.5 * ph;
    double x1 = pcx + 0.5 * pw, y1 = pcy + 0.5 * ph;
    x0 = x0 < 0.0 ? 0.0 : (x0 > 1024.0 ? 1024.0 : x0);
    y0 = y0 < 0.0 ? 0.0 : (y0 > 1024.0 ? 1024.0 : y0);
    x1 = x1 < 0.0 ? 0.0 : (x1 > 1024.0 ? 1024.0 : x1);
    y1 = y1 < 0.0 ? 0.0 : (y1 > 1024.0 ? 1024.0 : y1);
    bool vld = ((x1 - x0) > 0.0) && ((y1 - y0) > 0.0);

    bout[catpos] = make_float4((float)x0, (float)y0, (float)x1, (float)y1);
    double off = (double)lvl * 4096.0;
    double* op = obout + (size_t)catpos * 4;
    op[0] = x0 + off; op[1] = y0 + off; op[2] = x1 + off; op[3] = y1 + off;
    valid[catpos] = vld ? 1u : 0u;
  }
}

// ---------------- K4: per-image stable sort of 4768 candidates ------------
__global__ __launch_bounds__(1024)
void k_sort(const float* __restrict__ scat, const float4* __restrict__ b,
            const double* __restrict__ ob, const unsigned* __restrict__ valid,
            float* __restrict__ s_s, float4* __restrict__ b_s,
            double* __restrict__ ob_s, unsigned* __restrict__ valid_s) {
  __shared__ unsigned long long sk[8192];
  const int n = blockIdx.x;
  const int tid = threadIdx.x;
  for (int i = tid; i < 8192; i += 1024)
    sk[i] = (i < MCAT)
      ? ((unsigned long long)(~keyd(scat[n * MCAT + i])) << 32) | (unsigned)i
      : ~0ULL;
  __syncthreads();
  for (unsigned k2 = 2; k2 <= 8192; k2 <<= 1)
    for (unsigned j = k2 >> 1; j > 0; j >>= 1) {
      for (int m = 0; m < 8; ++m) {
        unsigned i = (unsigned)tid + (unsigned)m * 1024u;
        unsigned l = i ^ j;
        if (l > i) {
          unsigned long long a = sk[i], bb = sk[l];
          bool up = ((i & k2) == 0);
          if (up ? (a > bb) : (a < bb)) { sk[i] = bb; sk[l] = a; }
        }
      }
      __syncthreads();
    }
  for (int r = tid; r < MCAT; r += 1024) {
    unsigned long long kk = sk[r];
    unsigned pos = (unsigned)kk;
    unsigned d = ~(unsigned)(kk >> 32);
    s_s[n * MCAT + r] = invkey(d);
    b_s[n * MCAT + r] = b[n * MCAT + pos];
    const double* src = ob + ((size_t)n * MCAT + pos) * 4;
    double* dst = ob_s + ((size_t)n * MCAT + r) * 4;
    dst[0] = src[0]; dst[1] = src[1]; dst[2] = src[2]; dst[3] = src[3];
    valid_s[n * MCAT + r] = valid[n * MCAT + pos];
  }
}

// ---------------- K5: suppression bitmask (fp64 IoU, j>i bits) ------------
__global__ __launch_bounds__(256)
void k_mask(const double* __restrict__ ob_s, unsigned long long* __restrict__ mask) {
  const int n = blockIdx.y;
  const int i = blockIdx.x;
  const double* bi = ob_s + ((size_t)n * MCAT + i) * 4;
  const double ix0 = bi[0], iy0 = bi[1], ix1 = bi[2], iy1 = bi[3];
  const double ai = (ix1 - ix0) * (iy1 - iy0);
  const int tid = threadIdx.x;
  for (int j0 = 0; j0 < MCAT; j0 += 256) {
    int j = j0 + tid;
    bool sup = false;
    if (j < MCAT && j > i) {
      const double* bj = ob_s + ((size_t)n * MCAT + j) * 4;
      double jx0 = bj[0], jy0 = bj[1], jx1 = bj[2], jy1 = bj[3];
      double aj = (jx1 - jx0) * (jy1 - jy0);
      double lx = ix0 > jx0 ? ix0 : jx0;
      double ly = iy0 > jy0 ? iy0 : jy0;
      double rx = ix1 < jx1 ? ix1 : jx1;
      double ry = iy1 < jy1 ? iy1 : jy1;
      double wx = rx - lx; wx = wx > 0.0 ? wx : 0.0;
      double wy = ry - ly; wy = wy > 0.0 ? wy : 0.0;
      double inter = wx * wy;
      double iou = inter / (ai + aj - inter + 1e-9);
      sup = iou > 0.7;
    }
    unsigned long long bal = __ballot(sup);
    if ((tid & 63) == 0) {
      int word = (j0 + tid) >> 6;
      if (word < MW) mask[((size_t)n * MCAT + i) * MW + word] = bal;
    }
  }
}

// ---------------- K6: greedy NMS scan (parallel rem-update) + output ------
__global__ __launch_bounds__(256)
void k_nms(const unsigned long long* __restrict__ mask,
           const unsigned* __restrict__ valid_s,
           const float* __restrict__ s_s, const float4* __restrict__ b_s,
           float* __restrict__ out) {
  __shared__ unsigned long long rem[MW];
  __shared__ unsigned long long supcc[64];
  __shared__ unsigned long long keepw[MW];
  __shared__ int kl[64];
  __shared__ int snk;
  __shared__ unsigned kpfx[MW], nkpfx[MW];
  __shared__ unsigned sKept;
  const int n = blockIdx.x;
  const int tid = threadIdx.x;
  const unsigned long long* msk = mask + (size_t)n * MCAT * MW;

  for (int w = tid; w < MW; w += 256) {
    unsigned long long r = 0ULL;
    for (int b = 0; b < 64; ++b) {
      int i = w * 64 + b;
      bool rm = (i >= MCAT) || (valid_s[n * MCAT + i] == 0u);
      if (rm) r |= (1ULL << b);
    }
    rem[w] = r;
    keepw[w] = 0ULL;
  }
  __syncthreads();

  for (int c = 0; c < MW; ++c) {
    if (tid < 64) {
      int i = c * 64 + tid;
      supcc[tid] = (i < MCAT) ? msk[(size_t)i * MW + c] : 0ULL;
    }
    __syncthreads();
    if (tid == 0) {
      unsigned long long r = rem[c], km = 0ULL;
      int nk = 0;
      for (int b = 0; b < 64; ++b) {
        if (!((r >> b) & 1ULL)) { km |= (1ULL << b); kl[nk++] = b; r |= supcc[b]; }
      }
      rem[c] = r; keepw[c] = km; snk = nk;
    }
    __syncthreads();
    const int nk = snk;
    const int nw = MW - 1 - c;
    const int total = nk * nw;
    for (int idx = tid; idx < total; idx += 256) {
      int b = kl[idx / nw];
      int w = c + 1 + (idx % nw);
      unsigned long long v = msk[(size_t)(c * 64 + b) * MW + w];
      if (v) atomicOr(&rem[w], v);
    }
    __syncthreads();
  }

  if (tid == 0) {
    unsigned ka = 0, na = 0;
    for (int w = 0; w < MW; ++w) {
      kpfx[w] = ka; nkpfx[w] = na;
      unsigned long long range = (w < MW - 1) ? ~0ULL : ((1ULL << 32) - 1ULL);
      ka += (unsigned)__popcll(keepw[w]);
      na += (unsigned)__popcll((~keepw[w]) & range);
    }
    sKept = ka;
  }
  __syncthreads();
  const unsigned keptTotal = sKept;

  for (int i = tid; i < MCAT; i += 256) {
    int w = i >> 6, b = i & 63;
    unsigned long long below = (1ULL << b) - 1ULL;
    bool kept = (keepw[w] >> b) & 1ULL;
    unsigned row;
    if (kept)
      row = kpfx[w] + (unsigned)__popcll(keepw[w] & below);
    else
      row = keptTotal + nkpfx[w] + (unsigned)__popcll((~keepw[w]) & below);
    if (row < 1000u) {
      float4 bb = b_s[n * MCAT + i];
      float sc = kept ? s_s[n * MCAT + i] : -1e4f;
      float* o = out + ((size_t)n * 1000 + row) * 5;
      o[0] = bb.x; o[1] = bb.y; o[2] = bb.z; o[3] = bb.w; o[4] = sc;
    }
  }
}

// ---------------- launch ----------------
extern "C" void kernel_launch(void* const* d_in, const int* in_sizes, int n_in,
                              void* d_out, int out_size, void* d_ws, size_t ws_size,
                              hipStream_t stream) {
  (void)in_sizes; (void)n_in; (void)out_size;
  const float* feats[5] = {(const float*)d_in[0], (const float*)d_in[1],
                           (const float*)d_in[2], (const float*)d_in[3],
                           (const float*)d_in[4]};
  const float* w_conv = (const float*)d_in[5];
  const float* b_conv = (const float*)d_in[6];
  const float* w_obj  = (const float*)d_in[7];
  const float* b_obj  = (const float*)d_in[8];
  const float* w_del  = (const float*)d_in[9];
  const float* b_del  = (const float*)d_in[10];
  float* out = (float*)d_out;

  char* p = (char*)d_ws;
  auto alloc = [&](size_t bytes) -> void* {
    void* r = (void*)p;
    p += (bytes + 255) & ~(size_t)255;
    return r;
  };
  float*  t       = (float*)  alloc((size_t)2 * 256 * 256 * 256 * 4); // 134 MB, lvl1-4 then lvl0
  float*  wT      = (float*)  alloc((size_t)2304 * 256 * 4);
  float*  logits  = (float*)  alloc((size_t)NIMG * LTOT * 4);
  float4* deltas  = (float4*) alloc((size_t)NIMG * LTOT * 16);
  float*  scat    = (float*)  alloc((size_t)NIMG * MCAT * 4);
  float4* bout    = (float4*) alloc((size_t)NIMG * MCAT * 16);
  double* obout   = (double*) alloc((size_t)NIMG * MCAT * 32);
  unsigned* valid = (unsigned*)alloc((size_t)NIMG * MCAT * 4);
  float*  s_s     = (float*)  alloc((size_t)NIMG * MCAT * 4);
  float4* b_s     = (float4*) alloc((size_t)NIMG * MCAT * 16);
  double* ob_s    = (double*) alloc((size_t)NIMG * MCAT * 32);
  unsigned* val_s = (unsigned*)alloc((size_t)NIMG * MCAT * 4);
  unsigned long long* mask =
      (unsigned long long*)alloc((size_t)NIMG * MCAT * MW * 8);
  if ((size_t)(p - (char*)d_ws) > ws_size) return;

  k_wT<<<2304, 256, 0, stream>>>(w_conv, wT);

  // levels 1-4 fused (t[0..11141120)), heads4 consumes, then level 0 reuses t
  k_conv4<<<736, 256, 0, stream>>>(feats[1], feats[2], feats[3], feats[4],
                                   wT, b_conv, t);
  k_heads4<<<dim3(22, 2), 256, 0, stream>>>(t, w_obj, b_obj, w_del, b_del,
                                            logits, deltas);
  k_conv0<<<dim3(4, 64, 8), 256, 0, stream>>>(feats[0], wT, b_conv, t);
  k_heads0<<<dim3(64, 2), 256, 0, stream>>>(t, w_obj, b_obj, w_del, b_del,
                                            logits, deltas);

  k_topk<<<10, 1024, 0, stream>>>(logits, deltas, scat, bout, obout, valid);
  k_sort<<<2, 1024, 0, stream>>>(scat, bout, obout, valid, s_s, b_s, ob_s, val_s);
  k_mask<<<dim3(MCAT, 2), 256, 0, stream>>>(ob_s, mask);
  k_nms<<<2, 256, 0, stream>>>(mask, val_s, s_s, b_s, out);
}